// Round 6
// baseline (161.673 us; speedup 1.0000x reference)
//
#include <hip/hip_runtime.h>
#include <stdint.h>

// Problem constants (fixed by the reference):
#define BB     16
#define NTOK   16384
#define GG     128
#define NGMAX  128
#define DD     256
#define NCHUNK (NTOK / 64)      // 256 64-token chunks per sample

typedef unsigned short     u16;
typedef unsigned int       u32;
typedef unsigned long long u64;
typedef uint8_t            u8;

// Native clang vector types — required by __builtin_nontemporal_*:
typedef int   __attribute__((ext_vector_type(4))) i4;
typedef float __attribute__((ext_vector_type(4))) f4;

// Workspace layout:
//   pack16[B*N]          (512 KB): per token, (g << 8) | chunk_rank. g=255 => uncovered.
//   hist  [B][G][NCHUNK]   (2 MB): per-chunk per-g counts -> exclusive prefix over chunks.

// ---------------------------------------------------------------------------
// Kernel 1 (fused): per-64-token chunk — last-g scan + ordered rank + hist.
// Phase A: 4 lanes/token read the 512B onehot row (8 x 16B each; per j-step
//          4 lanes cover 64B contiguous), keep LAST positive index, reduce
//          over the 4 lanes, leader drops g into LDS.
// Phase B: wave 0 ballots 8 bit-planes of g over the 64 tokens:
//          rank = popc(same & below); histogram WITHOUT memset (lane l
//          reconstructs counts for g=l and g=l+64 from the planes).
// ---------------------------------------------------------------------------
__global__ __launch_bounds__(256) void k_stage1(const float* __restrict__ onehot,
                                                u16* __restrict__ pack,
                                                u32* __restrict__ hist) {
    __shared__ u8 gsh[64];
    int tid   = threadIdx.x;
    int chunk = blockIdx.x;                 // 0 .. BB*NCHUNK-1
    int tok   = tid >> 2;                   // token within chunk, 0..63
    int part  = tid & 3;
    const float* base = onehot + ((size_t)chunk * 64 + tok) * GG;

    int best = -1;
#pragma unroll
    for (int j = 0; j < 8; ++j) {
        int e = part * 32 + j * 4;          // fp32 > 0 <=> int bits > 0 (0.0/1.0 data)
        i4 v = __builtin_nontemporal_load(reinterpret_cast<const i4*>(base + e));
        if (v.x > 0) best = e + 0;
        if (v.y > 0) best = e + 1;
        if (v.z > 0) best = e + 2;
        if (v.w > 0) best = e + 3;
    }
    best = max(best, __shfl_xor(best, 1));
    best = max(best, __shfl_xor(best, 2));
    if (part == 0) gsh[tok] = (best < 0) ? (u8)255 : (u8)best;
    __syncthreads();

    if (tid < 64) {                         // wave 0 only (wave-uniform branch)
        int lane = tid;
        unsigned g = gsh[lane];             // 0..127 or 255

        u64 plane[8];
#pragma unroll
        for (int bit = 0; bit < 8; ++bit)
            plane[bit] = __ballot((g >> bit) & 1u);

        u64 same = ~0ull;
#pragma unroll
        for (int bit = 0; bit < 8; ++bit)
            same &= ((g >> bit) & 1u) ? plane[bit] : ~plane[bit];
        u64 below = ((u64)1 << lane) - 1;
        unsigned rank = (unsigned)__popcll(same & below);   // <= 63
        pack[chunk * 64 + lane] = (u16)((g << 8) | rank);

        int b  = chunk >> 8;                // chunk / NCHUNK
        int cb = chunk & (NCHUNK - 1);
#pragma unroll
        for (int h = 0; h < 2; ++h) {
            unsigned tg = (unsigned)lane + h * 64;   // bit7==0 excludes sentinel
            u64 m = ~0ull;
#pragma unroll
            for (int bit = 0; bit < 8; ++bit)
                m &= ((tg >> bit) & 1u) ? plane[bit] : ~plane[bit];
            hist[((size_t)(b * GG + tg)) * NCHUNK + cb] = (u32)__popcll(m);
        }
    }
}

// ---------------------------------------------------------------------------
// Kernel 2: exclusive prefix over the NCHUNK counts per (b,g), one wave each.
// uint4 per lane (contiguous 1KB row), shuffle-up wave scan.
// ---------------------------------------------------------------------------
__global__ __launch_bounds__(64) void k_scan(u32* __restrict__ hist) {
    int pair = blockIdx.x;                  // b*GG + g
    int lane = threadIdx.x;
    u32* row = hist + (size_t)pair * NCHUNK;

    uint4 v = *reinterpret_cast<uint4*>(row + lane * 4);
    u32 s0 = v.x, s1 = s0 + v.y, s2 = s1 + v.z, s3 = s2 + v.w;
    u32 tot = s3, inc = tot;
#pragma unroll
    for (int o = 1; o < 64; o <<= 1) {
        u32 t = __shfl_up(inc, o);
        if (lane >= o) inc += t;
    }
    u32 excl = inc - tot;
    uint4 w;
    w.x = excl;
    w.y = excl + s0;
    w.z = excl + s1;
    w.w = excl + s2;
    *reinterpret_cast<uint4*>(row + lane * 4) = w;
}

// ---------------------------------------------------------------------------
// Kernel 3: gather the 1KB fp32 feature row per token. 16 lanes per token,
// 4 x 16B each. k = chunk_rank + chunk_offset, clipped to NGMAX-1.
// Non-temporal on the single-use streams (feat in, out out).
// ---------------------------------------------------------------------------
__global__ __launch_bounds__(256) void k_gather(const float* __restrict__ feat,
                                                const u16* __restrict__ pack,
                                                const u32* __restrict__ hist,
                                                float* __restrict__ out) {
    int tid   = threadIdx.x;
    int token = blockIdx.x * 16 + (tid >> 4);
    int inner = tid & 15;
    int b     = token >> 14;                // token / NTOK
    int n     = token & (NTOK - 1);

    unsigned p = pack[token];
    unsigned g = p >> 8;
    unsigned r = p & 0xFFu;

    f4 vals[4];
    if (g < GG) {
        u32 k = r + hist[((size_t)(b * GG + g)) * NCHUNK + (n >> 6)];
        if (k > NGMAX - 1) k = NGMAX - 1;
        const float* src = feat + (((size_t)(b * GG + g)) * NGMAX + k) * DD;
#pragma unroll
        for (int j = 0; j < 4; ++j)
            vals[j] = __builtin_nontemporal_load(
                reinterpret_cast<const f4*>(src + inner * 4 + j * 64));
    } else {
#pragma unroll
        for (int j = 0; j < 4; ++j) vals[j] = (f4){0.f, 0.f, 0.f, 0.f};
    }
    float* dst = out + (size_t)token * DD;
#pragma unroll
    for (int j = 0; j < 4; ++j)
        __builtin_nontemporal_store(vals[j],
            reinterpret_cast<f4*>(dst + inner * 4 + j * 64));
}

// ---------------------------------------------------------------------------
extern "C" void kernel_launch(void* const* d_in, const int* in_sizes, int n_in,
                              void* d_out, int out_size, void* d_ws, size_t ws_size,
                              hipStream_t stream) {
    const float* feat   = (const float*)d_in[0];   // [B,G,NGMAX,D] fp32
    const float* onehot = (const float*)d_in[1];   // [B,N,G] fp32
    float*       out    = (float*)d_out;           // [B,N,D] fp32

    u16* pack = (u16*)d_ws;                                        // 512 KB
    u32* hist = (u32*)((char*)d_ws + (size_t)BB * NTOK * 2);       // 2 MB

    k_stage1<<<BB * NCHUNK,     256, 0, stream>>>(onehot, pack, hist);
    k_scan  <<<BB * GG,         64,  0, stream>>>(hist);
    k_gather<<<BB * NTOK / 16,  256, 0, stream>>>(feat, pack, hist, out);
}

// Round 7
// 133.068 us; speedup vs baseline: 1.2150x; 1.2150x over previous
//
#include <hip/hip_runtime.h>
#include <stdint.h>

// Problem constants (fixed by the reference):
#define BB     16
#define NTOK   16384
#define GG     128
#define NGMAX  128
#define DD     256
#define NCHUNK (NTOK / 64)      // 256 64-token chunks per sample

typedef unsigned short     u16;
typedef unsigned int       u32;
typedef unsigned long long u64;
typedef uint8_t            u8;

// Workspace layout:
//   pack16[B*N]          (512 KB): per token, (g << 8) | chunk_rank. g=255 => uncovered.
//   hist  [B][G][NCHUNK]   (2 MB): per-chunk per-g counts -> exclusive prefix over chunks.

// ---------------------------------------------------------------------------
// Kernel 1 (fused): per-64-token chunk — last-g scan + ordered rank + hist.
// Phase A: 4 lanes/token read the 512B onehot row; e = part*4 + j*16 so the
//          4 lanes of a token cover one full 64B-aligned line per j-step
//          (wave footprint per instruction: 16 x 64B aligned chunks).
//          Keep LAST positive index; reduce over the 4 lanes; leader -> LDS.
// Phase B: wave 0 ballots 8 bit-planes of g over the 64 tokens:
//          rank = popc(same & below); histogram WITHOUT memset (lane l
//          reconstructs counts for g=l and g=l+64 from the planes).
// ---------------------------------------------------------------------------
__global__ __launch_bounds__(256) void k_stage1(const float* __restrict__ onehot,
                                                u16* __restrict__ pack,
                                                u32* __restrict__ hist) {
    __shared__ u8 gsh[64];
    int tid   = threadIdx.x;
    int chunk = blockIdx.x;                 // 0 .. BB*NCHUNK-1
    int tok   = tid >> 2;                   // token within chunk, 0..63
    int part  = tid & 3;
    const float* base = onehot + ((size_t)chunk * 64 + tok) * GG;

    int best = -1;
#pragma unroll
    for (int j = 0; j < 8; ++j) {
        int e = part * 4 + j * 16;          // fp32 > 0 <=> int bits > 0 (0.0/1.0 data)
        int4 v = *reinterpret_cast<const int4*>(base + e);
        if (v.x > 0) best = e + 0;
        if (v.y > 0) best = e + 1;
        if (v.z > 0) best = e + 2;
        if (v.w > 0) best = e + 3;
    }
    best = max(best, __shfl_xor(best, 1));
    best = max(best, __shfl_xor(best, 2));
    if (part == 0) gsh[tok] = (best < 0) ? (u8)255 : (u8)best;
    __syncthreads();

    if (tid < 64) {                         // wave 0 only (wave-uniform branch)
        int lane = tid;
        unsigned g = gsh[lane];             // 0..127 or 255

        u64 plane[8];
#pragma unroll
        for (int bit = 0; bit < 8; ++bit)
            plane[bit] = __ballot((g >> bit) & 1u);

        u64 same = ~0ull;
#pragma unroll
        for (int bit = 0; bit < 8; ++bit)
            same &= ((g >> bit) & 1u) ? plane[bit] : ~plane[bit];
        u64 below = ((u64)1 << lane) - 1;
        unsigned rank = (unsigned)__popcll(same & below);   // <= 63
        pack[chunk * 64 + lane] = (u16)((g << 8) | rank);

        int b  = chunk >> 8;                // chunk / NCHUNK
        int cb = chunk & (NCHUNK - 1);
#pragma unroll
        for (int h = 0; h < 2; ++h) {
            unsigned tg = (unsigned)lane + h * 64;   // bit7==0 excludes sentinel
            u64 m = ~0ull;
#pragma unroll
            for (int bit = 0; bit < 8; ++bit)
                m &= ((tg >> bit) & 1u) ? plane[bit] : ~plane[bit];
            hist[((size_t)(b * GG + tg)) * NCHUNK + cb] = (u32)__popcll(m);
        }
    }
}

// ---------------------------------------------------------------------------
// Kernel 2: exclusive prefix over the NCHUNK counts per (b,g), one wave each.
// uint4 per lane (contiguous 1KB row), shuffle-up wave scan.
// ---------------------------------------------------------------------------
__global__ __launch_bounds__(64) void k_scan(u32* __restrict__ hist) {
    int pair = blockIdx.x;                  // b*GG + g
    int lane = threadIdx.x;
    u32* row = hist + (size_t)pair * NCHUNK;

    uint4 v = *reinterpret_cast<uint4*>(row + lane * 4);
    u32 s0 = v.x, s1 = s0 + v.y, s2 = s1 + v.z, s3 = s2 + v.w;
    u32 tot = s3, inc = tot;
#pragma unroll
    for (int o = 1; o < 64; o <<= 1) {
        u32 t = __shfl_up(inc, o);
        if (lane >= o) inc += t;
    }
    u32 excl = inc - tot;
    uint4 w;
    w.x = excl;
    w.y = excl + s0;
    w.z = excl + s1;
    w.w = excl + s2;
    *reinterpret_cast<uint4*>(row + lane * 4) = w;
}

// ---------------------------------------------------------------------------
// Kernel 3: gather the 1KB fp32 feature row per token. 16 lanes per token,
// 4 x 16B each. k = chunk_rank + chunk_offset, clipped to NGMAX-1.
// (round-4 exact form — plain loads/stores, no nt)
// ---------------------------------------------------------------------------
__global__ __launch_bounds__(256) void k_gather(const float* __restrict__ feat,
                                                const u16* __restrict__ pack,
                                                const u32* __restrict__ hist,
                                                float* __restrict__ out) {
    int tid   = threadIdx.x;
    int token = blockIdx.x * 16 + (tid >> 4);
    int inner = tid & 15;
    int b     = token >> 14;                // token / NTOK
    int n     = token & (NTOK - 1);

    unsigned p = pack[token];
    unsigned g = p >> 8;
    unsigned r = p & 0xFFu;

    float4 vals[4];
    if (g < GG) {
        u32 k = r + hist[((size_t)(b * GG + g)) * NCHUNK + (n >> 6)];
        if (k > NGMAX - 1) k = NGMAX - 1;
        const float* src = feat + (((size_t)(b * GG + g)) * NGMAX + k) * DD;
#pragma unroll
        for (int j = 0; j < 4; ++j)
            vals[j] = *reinterpret_cast<const float4*>(src + inner * 4 + j * 64);
    } else {
#pragma unroll
        for (int j = 0; j < 4; ++j) vals[j] = make_float4(0.f, 0.f, 0.f, 0.f);
    }
    float* dst = out + (size_t)token * DD;
#pragma unroll
    for (int j = 0; j < 4; ++j)
        *reinterpret_cast<float4*>(dst + inner * 4 + j * 64) = vals[j];
}

// ---------------------------------------------------------------------------
extern "C" void kernel_launch(void* const* d_in, const int* in_sizes, int n_in,
                              void* d_out, int out_size, void* d_ws, size_t ws_size,
                              hipStream_t stream) {
    const float* feat   = (const float*)d_in[0];   // [B,G,NGMAX,D] fp32
    const float* onehot = (const float*)d_in[1];   // [B,N,G] fp32
    float*       out    = (float*)d_out;           // [B,N,D] fp32

    u16* pack = (u16*)d_ws;                                        // 512 KB
    u32* hist = (u32*)((char*)d_ws + (size_t)BB * NTOK * 2);       // 2 MB

    k_stage1<<<BB * NCHUNK,     256, 0, stream>>>(onehot, pack, hist);
    k_scan  <<<BB * GG,         64,  0, stream>>>(hist);
    k_gather<<<BB * NTOK / 16,  256, 0, stream>>>(feat, pack, hist, out);
}